// Round 6
// baseline (177.614 us; speedup 1.0000x reference)
//
#include <hip/hip_runtime.h>

// Problem constants
constexpr int Cc = 64, Oc = 64, Gc = 16, Ec = 128, Wc = 7;
constexpr int Dc = 4, Nc = 4, Bc = 2, Tc = 512, TTc = 256, FOc = 64;
constexpr float EPSf = 1e-5f, LEAKYf = 0.01f;
constexpr unsigned NBLK = 1024;   // Bc*Gc*32 = exactly 4 blocks/CU on 256 CUs
// M = B*D*E*t*W = 2*4*128*256*7
constexpr float Minv = 1.0f / 1835008.0f;

// ws layout: partials[1024][8] floats (32 KB; row bid owned by block bid, no
// init needed), then a 4-byte barrier counter zeroed by hipMemsetAsync.
//
// Single-kernel design notes (R2/R4 post-mortems):
//  - conv runs AFTER the barrier wait: nothing register-heavy is live across
//    the opaque spin loop -> no spill (R4's failure: accs live across spin,
//    VGPR 64 + 124 MB scratch writes).
//  - spin polls RELAXED agent-scope + s_sleep, one acquire fence at exit (no
//    invalidate storm; R2's failure).
//  - 1024 blocks @ 4/CU: LDS ~35.4 KB x 4 = 142 KB <= 160 KB;
//    launch_bounds(256,4) binds VGPR <= 128. Grid == resident capacity ->
//    all blocks co-resident, barrier deadlock-free (proven in R4).
//  - stats math proven end-to-end in R4 (passed): mean/E[y^2] are linear
//    functionals of per-row parity sums of x,x^2 +- 5 edge elements.

// x LDS layout (verified R0/R2/R3/R4/R5): per row (16 rows = fl*8 + dd*2 +
// f2), padded q-index (q = t''+4; zeros at q<4, q>=516) stored as float4
// chunks c = q>>2, chunk c at float4-index (c&3)*33 + (c>>2) (132 f4/row).
__device__ __forceinline__ int FL4(int c) { return (c & 3) * 33 + (c >> 2); }

__global__ __launch_bounds__(256, 4) void fused_all(
    const float* __restrict__ x, const float* __restrict__ wgt,
    float* __restrict__ partials, unsigned* __restrict__ cnt,
    const float* __restrict__ gamma, const float* __restrict__ beta,
    float* __restrict__ out) {
  int bid = blockIdx.x;          // (b, g, fo2)
  int fo2 = bid & 31;
  int g   = (bid >> 5) & 15;
  int b   = bid >> 9;
  int t   = threadIdx.x;

  __shared__ float xs[16 * 528];   // 16 rows, chunk-interleaved (33792 B)
  __shared__ float wsm[512];       // [fl][lr8][n][8] (w 0..6 + pad)
  __shared__ float RS[16][4];      // per-row {Se, So, Se2, So2}
  __shared__ float SRT[8];         // reduced group stats
  __shared__ float sA[4], sC[4];   // per-n affine (a, c)
  float4* xs4 = (float4*)xs;

  // ---- stage x (row-per-thread-group) + in-register x/x^2 parity stats ----
  // thread t: row lr = t>>4, chunks c = 1 + (t&15) + 16k. Global reads are
  // 16-thread x 256B contiguous segments; LDS write aliasing <=2-way (free).
  int lr = t >> 4, sub = t & 15;
  int fl = lr >> 3, dd = (lr >> 1) & 3, f2 = lr & 1;
  const float4* src = (const float4*)(
      x + ((size_t)((b * Cc + g * Dc + dd) * Ec + 4 * fo2 + 2 * fl + f2)) * Tc);
  float se = 0.f, so = 0.f, se2 = 0.f, so2 = 0.f;
#pragma unroll
  for (int k = 0; k < 8; ++k) {
    float4 v = src[sub + 16 * k];
    xs4[lr * 132 + FL4(1 + sub + 16 * k)] = v;
    se += v.x + v.z;  so += v.y + v.w;    // float4 starts at even t''
    se2 += v.x * v.x + v.z * v.z;
    so2 += v.y * v.y + v.w * v.w;
  }
#pragma unroll
  for (int off = 1; off < 16; off <<= 1) {   // reduce over the 16 sub-threads
    se  += __shfl_xor(se, off);  so  += __shfl_xor(so, off);
    se2 += __shfl_xor(se2, off); so2 += __shfl_xor(so2, off);
  }
  if (sub == 0) { RS[lr][0] = se; RS[lr][1] = so; RS[lr][2] = se2; RS[lr][3] = so2; }
  if (t < 32) {  // zero pad chunks 0 and 129 of each row
    int lrp = t >> 1;
    int c = (t & 1) ? 129 : 0;
    xs4[lrp * 132 + FL4(c)] = make_float4(0.f, 0.f, 0.f, 0.f);
  }
  if (t < 128) {  // stage weights, padded to 8 per (fl,lr8,n)
#pragma unroll
    for (int i = 0; i < 4; ++i) {
      int s = t * 4 + i;
      int w = s & 7, n = (s >> 3) & 3, lr8 = (s >> 5) & 7, flS = s >> 8;
      int o = g * Nc + n, ddS = lr8 >> 1, f = 4 * fo2 + 2 * flS + (lr8 & 1);
      wsm[s] = (w < 7) ? wgt[((size_t)((o * Dc + ddS) * Ec + f)) * Wc + w] : 0.f;
    }
  }
  __syncthreads();

  // ---- publish block stat partials, then ARRIVE (wave 0 only) ----
  if (t < 64) {
    int r2 = t >> 2, n = t & 3;
    float Se = RS[r2][0], So = RS[r2][1], Se2 = RS[r2][2], So2 = RS[r2][3];
    const float* rowf = &xs[r2 * 528];
    // chunk 128 (q 512..515) at floats 128..131; chunk 1 (q 4..7) at 132..135
    float e509 = rowf[129], e510 = rowf[130], e511 = rowf[131];
    float e0 = rowf[132], e1 = rowf[133];
    float S[7] = {So - e509 - e511, Se - e510, So - e511, Se, So,
                  Se - e0, So - e1};
    float Q[7] = {So2 - e509 * e509 - e511 * e511, Se2 - e510 * e510,
                  So2 - e511 * e511, Se2, So2, Se2 - e0 * e0, So2 - e1 * e1};
    float md = 0.f, vd = 0.f;
#pragma unroll
    for (int w = 0; w < 7; ++w) {
      float wt = wsm[(r2 * 4 + n) * 8 + w];
      md += wt * S[w];
      vd += wt * wt * Q[w];
    }
#pragma unroll
    for (int off = 4; off < 64; off <<= 1) {   // reduce over r2, keep n
      md += __shfl_xor(md, off);
      vd += __shfl_xor(vd, off);
    }
    if (t < 4) {   // lane t holds block totals for channel n = t
      float* p = &partials[(size_t)bid * 8];
      p[t] = md;
      p[4 + t] = vd;
    }
    __threadfence();   // release: order partials stores before the arrive
    if (t == 0)
      __hip_atomic_fetch_add(cnt, 1u, __ATOMIC_RELEASE,
                             __HIP_MEMORY_SCOPE_AGENT);
  }

  // ---- wait: relaxed polls (no invalidate storm), acquire fence on exit ----
  // Nothing register-heavy is live here: staging regs dead, conv not started.
  if (t == 0) {
    int tries = 0;
    while (__hip_atomic_load(cnt, __ATOMIC_RELAXED, __HIP_MEMORY_SCOPE_AGENT) <
           NBLK) {
      __builtin_amdgcn_s_sleep(8);
      if (++tries > (1 << 17)) break;   // fail-not-hang safety valve
    }
    __threadfence();   // acquire: invalidate before cross-XCD partials reads
  }
  __syncthreads();

  // ---- group stats reduction (wave 0): 64 partial rows of group g ----
  if (t < 64) {
    int b2 = t >> 5, ftp = t & 31;
    const float* p = &partials[((size_t)(b2 * 512 + g * 32 + ftp)) * 8];
    float4 P0 = *(const float4*)p;
    float4 P1 = *(const float4*)(p + 4);
    float v0 = P0.x, v1 = P0.y, v2 = P0.z, v3 = P0.w;
    float v4 = P1.x, v5 = P1.y, v6 = P1.z, v7 = P1.w;
#pragma unroll
    for (int off = 1; off < 64; off <<= 1) {
      v0 += __shfl_xor(v0, off); v1 += __shfl_xor(v1, off);
      v2 += __shfl_xor(v2, off); v3 += __shfl_xor(v3, off);
      v4 += __shfl_xor(v4, off); v5 += __shfl_xor(v5, off);
      v6 += __shfl_xor(v6, off); v7 += __shfl_xor(v7, off);
    }
    if (t == 0) {
      SRT[0] = v0; SRT[1] = v1; SRT[2] = v2; SRT[3] = v3;
      SRT[4] = v4; SRT[5] = v5; SRT[6] = v6; SRT[7] = v7;
    }
  }
  __syncthreads();
  if (t < 4) {
    float mean = SRT[t] * Minv;
    float e2   = SRT[4 + t] * Minv;
    float var  = e2 - mean * mean;          // biased var, matches jnp.var
    int o = g * Nc + t;
    float a = gamma[o] * rsqrtf(var + EPSf);
    sA[t] = a;
    sC[t] = 56.0f * (beta[o] - a * mean);   // 2*D*W = 56 elements pooled
  }
  __syncthreads();

  // ---- conv from LDS (x read exactly once from global, ever) ----
  int wv = t >> 6, j = t & 63;
  int fo_l = wv >> 1, n0 = (wv & 1) * 2;
  float acc0[4] = {0.f, 0.f, 0.f, 0.f}, acc1[4] = {0.f, 0.f, 0.f, 0.f};
#pragma unroll
  for (int lr8 = 0; lr8 < 8; ++lr8) {
    const float4* rb = xs4 + (fo_l * 8 + lr8) * 132;
    float4 X0 = rb[FL4(2 * j)];
    float4 X1 = rb[FL4(2 * j + 1)];
    float4 X2 = rb[FL4(2 * j + 2)];
    float4 X3 = rb[FL4(2 * j + 3)];
    float xq[16] = {X0.x, X0.y, X0.z, X0.w, X1.x, X1.y, X1.z, X1.w,
                    X2.x, X2.y, X2.z, X2.w, X3.x, X3.y, X3.z, X3.w};
    const float4* wb = (const float4*)&wsm[((fo_l * 8 + lr8) * 4 + n0) * 8];
    float4 Wa0 = wb[0], Wa1 = wb[1], Wb0 = wb[2], Wb1 = wb[3];
    float wA[7] = {Wa0.x, Wa0.y, Wa0.z, Wa0.w, Wa1.x, Wa1.y, Wa1.z};
    float wB[7] = {Wb0.x, Wb0.y, Wb0.z, Wb0.w, Wb1.x, Wb1.y, Wb1.z};
#pragma unroll
    for (int w = 0; w < 7; ++w) {
#pragma unroll
      for (int s = 0; s < 4; ++s) {
        float xv = xq[2 * s + w + 1];  // q = 2*tt + w + 1, tt = 4j+s
        acc0[s] += xv * wA[w];
        acc1[s] += xv * wB[w];
      }
    }
  }

  // ---- apply affine + LeakyReLU, store ----
  float a0 = sA[n0], c0 = sC[n0];
  float a1 = sA[n0 + 1], c1 = sC[n0 + 1];
  int o0 = g * Nc + n0;
  int fo = fo2 * 2 + fo_l;
  float4 r0, r1;
  float u;
  u = a0 * acc0[0] + c0; r0.x = (u >= 0.f) ? u : LEAKYf * u;
  u = a0 * acc0[1] + c0; r0.y = (u >= 0.f) ? u : LEAKYf * u;
  u = a0 * acc0[2] + c0; r0.z = (u >= 0.f) ? u : LEAKYf * u;
  u = a0 * acc0[3] + c0; r0.w = (u >= 0.f) ? u : LEAKYf * u;
  u = a1 * acc1[0] + c1; r1.x = (u >= 0.f) ? u : LEAKYf * u;
  u = a1 * acc1[1] + c1; r1.y = (u >= 0.f) ? u : LEAKYf * u;
  u = a1 * acc1[2] + c1; r1.z = (u >= 0.f) ? u : LEAKYf * u;
  u = a1 * acc1[3] + c1; r1.w = (u >= 0.f) ? u : LEAKYf * u;
  *(float4*)(out + ((size_t)((b * Oc + o0) * FOc + fo)) * TTc + 4 * j) = r0;
  *(float4*)(out + ((size_t)((b * Oc + o0 + 1) * FOc + fo)) * TTc + 4 * j) = r1;
}

extern "C" void kernel_launch(void* const* d_in, const int* in_sizes, int n_in,
                              void* d_out, int out_size, void* d_ws, size_t ws_size,
                              hipStream_t stream) {
  (void)in_sizes; (void)n_in; (void)out_size; (void)ws_size;
  const float* x     = (const float*)d_in[0];
  const float* w     = (const float*)d_in[1];
  const float* gamma = (const float*)d_in[2];
  const float* beta  = (const float*)d_in[3];
  float* partials = (float*)d_ws;          // 1024*8 floats (32 KB)
  unsigned* cnt = (unsigned*)((char*)d_ws + 1024 * 8 * sizeof(float));
  hipMemsetAsync((void*)cnt, 0, sizeof(unsigned), stream);
  fused_all<<<dim3(NBLK), dim3(256), 0, stream>>>(x, w, partials, cnt, gamma,
                                                  beta, (float*)d_out);
}

// Round 7
// 123.651 us; speedup vs baseline: 1.4364x; 1.4364x over previous
//
#include <hip/hip_runtime.h>

// Problem constants
constexpr int Cc = 64, Oc = 64, Gc = 16, Ec = 128, Wc = 7;
constexpr int Dc = 4, Nc = 4, Bc = 2, Tc = 512, TTc = 256, FOc = 64;
constexpr float EPSf = 1e-5f, LEAKYf = 0.01f;
// M = B*D*E*t*W = 2*4*128*256*7
constexpr float Minv = 1.0f / 1835008.0f;

// ws layout:
//   [0)      partials[1024][8] floats (32 KB; row bid owned by block bid)
//   [32768)  flags[1024] u32 (4 KB)  -- per-block arrival flags
//   [36864)  go[16*32] u32 (2 KB)    -- per-group release words, 128 B apart
// flags+go (6 KB) are zeroed by one hipMemsetAsync each launch.
//
// Barrier design (R6 post-mortem): R6's single counter took ~105 us because
// 1024 agent-scope fetch_adds to ONE line serialize (~100 ns each) while 1024
// pollers steal the line. Here: arrival is a plain release-store to a
// DISTINCT dword per block (no RMW, no serialization); one leader per group
// sweeps its 64 flags with a single 64-lane load; followers poll only their
// group's go word. Release/acquire chain: block fence->flag, leader reads
// flags->fence->go, follower reads go->fence->partials (transitive).
//
// Conv runs AFTER the wait (R4 post-mortem: accs live across an opaque spin
// loop => scratch spill; R6 ordering compiled clean at VGPR 60).

// x LDS layout (verified R0/R2/R4/R5/R6): per row (16 rows = fl*8 + dd*2 +
// f2), padded q-index (q = t''+4; zeros at q<4, q>=516) stored as float4
// chunks c = q>>2, chunk c at float4-index (c&3)*33 + (c>>2) (132 f4/row).
__device__ __forceinline__ int FL4(int c) { return (c & 3) * 33 + (c >> 2); }

// 1024 blocks @ 4/CU (LDS 36352 B x 4 = 142 KB <= 160 KB; bounds(256,4) ->
// VGPR <= 128). Co-residency proven in R4/R6 (barriers completed).
__global__ __launch_bounds__(256, 4) void fused_all(
    const float* __restrict__ x, const float* __restrict__ wgt,
    float* __restrict__ partials, unsigned* __restrict__ flags,
    unsigned* __restrict__ go, const float* __restrict__ gamma,
    const float* __restrict__ beta, float* __restrict__ out) {
  int bid = blockIdx.x;          // (b, g, fo2)
  int fo2 = bid & 31;
  int g   = (bid >> 5) & 15;
  int b   = bid >> 9;
  int t   = threadIdx.x;

  __shared__ float xs[16 * 528];   // 16 rows, chunk-interleaved (33792 B)
  __shared__ float wsm[512];       // [fl][lr8][n][8] (w 0..6 + pad)
  __shared__ float RS[16][4];      // per-row {Se, So, Se2, So2}
  __shared__ float SRT[8];         // reduced group stats
  __shared__ float sA[4], sC[4];   // per-n affine (a, c)
  float4* xs4 = (float4*)xs;

  // ---- stage x (row-per-thread-group) + in-register x/x^2 parity stats ----
  int lr = t >> 4, sub = t & 15;
  int fl = lr >> 3, dd = (lr >> 1) & 3, f2 = lr & 1;
  const float4* src = (const float4*)(
      x + ((size_t)((b * Cc + g * Dc + dd) * Ec + 4 * fo2 + 2 * fl + f2)) * Tc);
  float se = 0.f, so = 0.f, se2 = 0.f, so2 = 0.f;
#pragma unroll
  for (int k = 0; k < 8; ++k) {
    float4 v = src[sub + 16 * k];
    xs4[lr * 132 + FL4(1 + sub + 16 * k)] = v;
    se += v.x + v.z;  so += v.y + v.w;    // float4 starts at even t''
    se2 += v.x * v.x + v.z * v.z;
    so2 += v.y * v.y + v.w * v.w;
  }
#pragma unroll
  for (int off = 1; off < 16; off <<= 1) {   // reduce over the 16 sub-threads
    se  += __shfl_xor(se, off);  so  += __shfl_xor(so, off);
    se2 += __shfl_xor(se2, off); so2 += __shfl_xor(so2, off);
  }
  if (sub == 0) { RS[lr][0] = se; RS[lr][1] = so; RS[lr][2] = se2; RS[lr][3] = so2; }
  if (t < 32) {  // zero pad chunks 0 and 129 of each row
    int lrp = t >> 1;
    int c = (t & 1) ? 129 : 0;
    xs4[lrp * 132 + FL4(c)] = make_float4(0.f, 0.f, 0.f, 0.f);
  }
  if (t < 128) {  // stage weights, padded to 8 per (fl,lr8,n)
#pragma unroll
    for (int i = 0; i < 4; ++i) {
      int s = t * 4 + i;
      int w = s & 7, n = (s >> 3) & 3, lr8 = (s >> 5) & 7, flS = s >> 8;
      int o = g * Nc + n, ddS = lr8 >> 1, f = 4 * fo2 + 2 * flS + (lr8 & 1);
      wsm[s] = (w < 7) ? wgt[((size_t)((o * Dc + ddS) * Ec + f)) * Wc + w] : 0.f;
    }
  }
  __syncthreads();

  // ---- publish block stat partials (wave 0), then ARRIVE via store ----
  if (t < 64) {
    int r2 = t >> 2, n = t & 3;
    float Se = RS[r2][0], So = RS[r2][1], Se2 = RS[r2][2], So2 = RS[r2][3];
    const float* rowf = &xs[r2 * 528];
    // chunk 128 (q 512..515) at floats 128..131; chunk 1 (q 4..7) at 132..135
    float e509 = rowf[129], e510 = rowf[130], e511 = rowf[131];
    float e0 = rowf[132], e1 = rowf[133];
    float S[7] = {So - e509 - e511, Se - e510, So - e511, Se, So,
                  Se - e0, So - e1};
    float Q[7] = {So2 - e509 * e509 - e511 * e511, Se2 - e510 * e510,
                  So2 - e511 * e511, Se2, So2, Se2 - e0 * e0, So2 - e1 * e1};
    float md = 0.f, vd = 0.f;
#pragma unroll
    for (int w = 0; w < 7; ++w) {
      float wt = wsm[(r2 * 4 + n) * 8 + w];
      md += wt * S[w];
      vd += wt * wt * Q[w];
    }
#pragma unroll
    for (int off = 4; off < 64; off <<= 1) {   // reduce over r2, keep n
      md += __shfl_xor(md, off);
      vd += __shfl_xor(vd, off);
    }
    if (t < 4) {   // lane t holds block totals for channel n = t
      float* p = &partials[(size_t)bid * 8];
      p[t] = md;
      p[4 + t] = vd;
    }
  }
  int gl = (b << 5) | fo2;   // group-local block id 0..63
  if (t == 0) {
    __threadfence();         // release: order partials stores before flag
    __hip_atomic_store(&flags[g * 64 + gl], 1u, __ATOMIC_RELAXED,
                       __HIP_MEMORY_SCOPE_AGENT);
  }

  // ---- per-group barrier wait: leader sweeps flags, followers poll go ----
  if (gl == 0) {
    if (t < 64) {   // leader wave: one 64-lane sweep of the group's flags
      int tries = 0;
      for (;;) {
        unsigned f = __hip_atomic_load(&flags[g * 64 + t], __ATOMIC_RELAXED,
                                       __HIP_MEMORY_SCOPE_AGENT);
        if (__all(f == 1u)) break;
        __builtin_amdgcn_s_sleep(2);
        if (++tries > (1 << 16)) break;   // fail-not-hang safety valve
      }
      if (t == 0) {
        __threadfence();   // order: flag reads happen-before go store
        __hip_atomic_store(&go[g * 32], 1u, __ATOMIC_RELAXED,
                           __HIP_MEMORY_SCOPE_AGENT);
      }
    }
  } else if (t == 0) {
    int tries = 0;
    while (__hip_atomic_load(&go[g * 32], __ATOMIC_RELAXED,
                             __HIP_MEMORY_SCOPE_AGENT) != 1u) {
      __builtin_amdgcn_s_sleep(8);
      if (++tries > (1 << 17)) break;     // fail-not-hang safety valve
    }
  }
  if (t == 0) __threadfence();   // acquire: invalidate before partials reads
  __syncthreads();

  // ---- group stats reduction (wave 0): 64 partial rows of group g ----
  if (t < 64) {
    int b2 = t >> 5, ftp = t & 31;
    const float* p = &partials[((size_t)(b2 * 512 + g * 32 + ftp)) * 8];
    float4 P0 = *(const float4*)p;
    float4 P1 = *(const float4*)(p + 4);
    float v0 = P0.x, v1 = P0.y, v2 = P0.z, v3 = P0.w;
    float v4 = P1.x, v5 = P1.y, v6 = P1.z, v7 = P1.w;
#pragma unroll
    for (int off = 1; off < 64; off <<= 1) {
      v0 += __shfl_xor(v0, off); v1 += __shfl_xor(v1, off);
      v2 += __shfl_xor(v2, off); v3 += __shfl_xor(v3, off);
      v4 += __shfl_xor(v4, off); v5 += __shfl_xor(v5, off);
      v6 += __shfl_xor(v6, off); v7 += __shfl_xor(v7, off);
    }
    if (t == 0) {
      SRT[0] = v0; SRT[1] = v1; SRT[2] = v2; SRT[3] = v3;
      SRT[4] = v4; SRT[5] = v5; SRT[6] = v6; SRT[7] = v7;
    }
  }
  __syncthreads();
  if (t < 4) {
    float mean = SRT[t] * Minv;
    float e2   = SRT[4 + t] * Minv;
    float var  = e2 - mean * mean;          // biased var, matches jnp.var
    int o = g * Nc + t;
    float a = gamma[o] * rsqrtf(var + EPSf);
    sA[t] = a;
    sC[t] = 56.0f * (beta[o] - a * mean);   // 2*D*W = 56 elements pooled
  }
  __syncthreads();

  // ---- conv from LDS (x read exactly once from global, ever) ----
  int wv = t >> 6, j = t & 63;
  int fo_l = wv >> 1, n0 = (wv & 1) * 2;
  float acc0[4] = {0.f, 0.f, 0.f, 0.f}, acc1[4] = {0.f, 0.f, 0.f, 0.f};
#pragma unroll
  for (int lr8 = 0; lr8 < 8; ++lr8) {
    const float4* rb = xs4 + (fo_l * 8 + lr8) * 132;
    float4 X0 = rb[FL4(2 * j)];
    float4 X1 = rb[FL4(2 * j + 1)];
    float4 X2 = rb[FL4(2 * j + 2)];
    float4 X3 = rb[FL4(2 * j + 3)];
    float xq[16] = {X0.x, X0.y, X0.z, X0.w, X1.x, X1.y, X1.z, X1.w,
                    X2.x, X2.y, X2.z, X2.w, X3.x, X3.y, X3.z, X3.w};
    const float4* wb = (const float4*)&wsm[((fo_l * 8 + lr8) * 4 + n0) * 8];
    float4 Wa0 = wb[0], Wa1 = wb[1], Wb0 = wb[2], Wb1 = wb[3];
    float wA[7] = {Wa0.x, Wa0.y, Wa0.z, Wa0.w, Wa1.x, Wa1.y, Wa1.z};
    float wB[7] = {Wb0.x, Wb0.y, Wb0.z, Wb0.w, Wb1.x, Wb1.y, Wb1.z};
#pragma unroll
    for (int w = 0; w < 7; ++w) {
#pragma unroll
      for (int s = 0; s < 4; ++s) {
        float xv = xq[2 * s + w + 1];  // q = 2*tt + w + 1, tt = 4j+s
        acc0[s] += xv * wA[w];
        acc1[s] += xv * wB[w];
      }
    }
  }

  // ---- apply affine + LeakyReLU, store ----
  float a0 = sA[n0], c0 = sC[n0];
  float a1 = sA[n0 + 1], c1 = sC[n0 + 1];
  int o0 = g * Nc + n0;
  int fo = fo2 * 2 + fo_l;
  float4 r0, r1;
  float u;
  u = a0 * acc0[0] + c0; r0.x = (u >= 0.f) ? u : LEAKYf * u;
  u = a0 * acc0[1] + c0; r0.y = (u >= 0.f) ? u : LEAKYf * u;
  u = a0 * acc0[2] + c0; r0.z = (u >= 0.f) ? u : LEAKYf * u;
  u = a0 * acc0[3] + c0; r0.w = (u >= 0.f) ? u : LEAKYf * u;
  u = a1 * acc1[0] + c1; r1.x = (u >= 0.f) ? u : LEAKYf * u;
  u = a1 * acc1[1] + c1; r1.y = (u >= 0.f) ? u : LEAKYf * u;
  u = a1 * acc1[2] + c1; r1.z = (u >= 0.f) ? u : LEAKYf * u;
  u = a1 * acc1[3] + c1; r1.w = (u >= 0.f) ? u : LEAKYf * u;
  *(float4*)(out + ((size_t)((b * Oc + o0) * FOc + fo)) * TTc + 4 * j) = r0;
  *(float4*)(out + ((size_t)((b * Oc + o0 + 1) * FOc + fo)) * TTc + 4 * j) = r1;
}

extern "C" void kernel_launch(void* const* d_in, const int* in_sizes, int n_in,
                              void* d_out, int out_size, void* d_ws, size_t ws_size,
                              hipStream_t stream) {
  (void)in_sizes; (void)n_in; (void)out_size; (void)ws_size;
  const float* x     = (const float*)d_in[0];
  const float* w     = (const float*)d_in[1];
  const float* gamma = (const float*)d_in[2];
  const float* beta  = (const float*)d_in[3];
  float* partials = (float*)d_ws;                       // 32 KB
  unsigned* flags = (unsigned*)((char*)d_ws + 32768);   // 4 KB
  unsigned* go    = (unsigned*)((char*)d_ws + 36864);   // 2 KB
  // zero flags + go (6 KB) each replay
  hipMemsetAsync((void*)flags, 0, 6144, stream);
  fused_all<<<dim3(1024), dim3(256), 0, stream>>>(x, w, partials, flags, go,
                                                  gamma, beta, (float*)d_out);
}

// Round 8
// 88.849 us; speedup vs baseline: 1.9990x; 1.3917x over previous
//
#include <hip/hip_runtime.h>

// Problem constants
constexpr int Cc = 64, Oc = 64, Gc = 16, Ec = 128, Wc = 7;
constexpr int Dc = 4, Nc = 4, Bc = 2, Tc = 512, TTc = 256, FOc = 64;
constexpr float EPSf = 1e-5f, LEAKYf = 0.01f;
// M = B*D*E*t*W = 2*4*128*256*7
constexpr float Minv = 1.0f / 1835008.0f;

// ws layout: partials[1024][8] floats (32 KB). Row bid (= b*512+g*32+ft) is
// owned exclusively by stats_k block bid -> no atomics, no init, no memset.
// p[0..3] = per-n mean partial, p[4..7] = per-n E[y^2] partial.
//
// Session decomposition (R0-R7): total = 62 us fixed harness share (256 MiB
// ws poison @ BW roofline + restores) + controllable. Two dispatches is the
// floor for training-mode BN: a device-wide intra-kernel barrier costs
// >= 37 us on this chip (R2/R6/R7: per-block device-scope fences serialize
// L2 tag-walks), exceeding the ~10 us saved by merging. This two-kernel
// form measured 89.0 us (R5) -- the structural optimum.
//
// Stats math (verified rounds 0/3/4/5): BN mean and E[y^2] are linear
// functionals of per-row windowed sums of x (S_w) and x^2 (Q_w); S_w/Q_w
// come from parity sums +- the 5 edge elements (t''=0,1,509,510,511).

// ---------------- K1: streaming stats over x ----------------
// grid: (b, g, ft) = 2*16*32 = 1024 blocks; 16 rows/block (d x 4 f), 16
// threads/row. Tiny LDS -> full occupancy, BW-bound on the 32 MB cold x read.
__global__ __launch_bounds__(256) void stats_k(const float* __restrict__ x,
                                               const float* __restrict__ wgt,
                                               float* __restrict__ partials) {
  int bid = blockIdx.x;
  int ft = bid & 31;            // f-tile: f = 4*ft + fi
  int g  = (bid >> 5) & 15;
  int b  = bid >> 9;
  int t  = threadIdx.x;

  __shared__ float RS[16][4];   // per-row {Se, So, Se2, So2}
  __shared__ float ED[16][5];   // per-row {e0, e1, e509, e510, e511}

  int r = t >> 4, sub = t & 15;
  int d = r >> 2, fi = r & 3;
  const float4* src = (const float4*)(
      x + ((size_t)((b * Cc + g * Dc + d) * Ec + 4 * ft + fi)) * Tc);

  float se = 0.f, so = 0.f, se2 = 0.f, so2 = 0.f;
#pragma unroll
  for (int k = 0; k < 8; ++k) {
    float4 v = src[sub + 16 * k];       // x[t''] at t'' = 4*(sub+16k)+e
    se += v.x + v.z;  so += v.y + v.w;  // float4 starts at even t''
    se2 += v.x * v.x + v.z * v.z;
    so2 += v.y * v.y + v.w * v.w;
    if (k == 0 && sub == 0) { ED[r][0] = v.x; ED[r][1] = v.y; }
    if (k == 7 && sub == 15) { ED[r][2] = v.y; ED[r][3] = v.z; ED[r][4] = v.w; }
  }
#pragma unroll
  for (int off = 1; off < 16; off <<= 1) {   // reduce over sub (in-wave)
    se  += __shfl_xor(se, off);  so  += __shfl_xor(so, off);
    se2 += __shfl_xor(se2, off); so2 += __shfl_xor(so2, off);
  }
  if (sub == 0) { RS[r][0] = se; RS[r][1] = so; RS[r][2] = se2; RS[r][3] = so2; }
  __syncthreads();

  // phase 2: wave 0 only; thread t = r2*4 + n
  float md = 0.f, vd = 0.f;
  if (t < 64) {
    int r2 = t >> 2, n = t & 3;
    float Se = RS[r2][0], So = RS[r2][1], Se2 = RS[r2][2], So2 = RS[r2][3];
    float e0 = ED[r2][0], e1 = ED[r2][1];
    float e509 = ED[r2][2], e510 = ED[r2][3], e511 = ED[r2][4];
    float S[7] = {So - e509 - e511, Se - e510, So - e511, Se, So,
                  Se - e0, So - e1};
    float Q[7] = {So2 - e509 * e509 - e511 * e511, Se2 - e510 * e510,
                  So2 - e511 * e511, Se2, So2, Se2 - e0 * e0, So2 - e1 * e1};
    int d2 = r2 >> 2, fi2 = r2 & 3;
    int o = g * Nc + n;
    const float* wp = wgt + ((size_t)((o * Dc + d2) * Ec + 4 * ft + fi2)) * Wc;
#pragma unroll
    for (int w = 0; w < 7; ++w) {
      float wt = wp[w];
      md += wt * S[w];
      vd += wt * wt * Q[w];
    }
#pragma unroll
    for (int off = 4; off < 64; off <<= 1) {   // reduce over r2, keep n = t&3
      md += __shfl_xor(md, off);
      vd += __shfl_xor(vd, off);
    }
    if (t < 4) {   // lane t holds block totals for channel n = t
      float* p = &partials[(size_t)bid * 8];
      p[t] = md;
      p[4 + t] = vd;
    }
  }
}

// ---------------- K2: conv + stats-finish + affine + LeakyReLU ----------------
// x LDS layout (verified rounds 0/2/3): per row (16 rows = fl*8 + dd*2 + f2),
// padded q-index (q = t''+4; zeros at q<4, q>=516) stored as float4 chunks
// c = q>>2, chunk c at float4-index (c&3)*33 + (c>>2) (132 float4/row).
__device__ __forceinline__ int FL4(int c) { return (c & 3) * 33 + (c >> 2); }

// LDS ~35.9 KB -> 4 blocks/CU; launch_bounds(256,4) binds VGPR <= 128.
__global__ __launch_bounds__(256, 4) void conv_k(
    const float* __restrict__ x, const float* __restrict__ wgt,
    const float* __restrict__ partials, const float* __restrict__ gamma,
    const float* __restrict__ beta, float* __restrict__ out) {
  int bid = blockIdx.x;          // (b, g, fo2)
  int fo2 = bid & 31;
  int g   = (bid >> 5) & 15;
  int b   = bid >> 9;
  int t   = threadIdx.x;

  __shared__ float xs[16 * 528];   // 16 rows, chunk-interleaved (33792 B)
  __shared__ float wsm[512];       // [fl][lr8][n][8] (w 0..6 + pad)
  __shared__ float SRT[8];         // reduced group stats
  float4* xs4 = (float4*)xs;

  // ---- stage x: 16 rows x 128 float4, fully coalesced (L3-hot after K1) ----
#pragma unroll
  for (int kk = 0; kk < 8; ++kk) {
    int idx = t + 256 * kk;
    int lr = idx >> 7, jj = idx & 127;
    int flS = lr >> 3, dd = (lr >> 1) & 3, f2 = lr & 1;
    const float4* src = (const float4*)(
        x + ((size_t)((b * Cc + g * Dc + dd) * Ec + 4 * fo2 + 2 * flS + f2)) * Tc);
    float4 v = src[jj];
    xs4[lr * 132 + FL4(jj + 1)] = v;   // q0 = 4 + 4*jj -> chunk jj+1
  }
  if (t < 32) {  // zero pad chunks 0 and 129 of each row
    int lr = t >> 1;
    int c = (t & 1) ? 129 : 0;
    xs4[lr * 132 + FL4(c)] = make_float4(0.f, 0.f, 0.f, 0.f);
  }
  if (t < 128) {  // stage weights, padded to 8 per (fl,lr8,n)
#pragma unroll
    for (int i = 0; i < 4; ++i) {
      int s = t * 4 + i;
      int w = s & 7, n = (s >> 3) & 3, lr8 = (s >> 5) & 7, flS = s >> 8;
      int o = g * Nc + n, dd = lr8 >> 1, f = 4 * fo2 + 2 * flS + (lr8 & 1);
      wsm[s] = (w < 7) ? wgt[((size_t)((o * Dc + dd) * Ec + f)) * Wc + w] : 0.f;
    }
  }
  // ---- group stats reduction (wave 0, overlapped with staging loads) ----
  // 64 partial rows of group g: (b2, ft) = (t>>5, t&31); 2 KB, L2-hot.
  if (t < 64) {
    int b2 = t >> 5, ftp = t & 31;
    const float* p = &partials[((size_t)(b2 * 512 + g * 32 + ftp)) * 8];
    float4 P0 = *(const float4*)p;
    float4 P1 = *(const float4*)(p + 4);
    float v0 = P0.x, v1 = P0.y, v2 = P0.z, v3 = P0.w;
    float v4 = P1.x, v5 = P1.y, v6 = P1.z, v7 = P1.w;
#pragma unroll
    for (int off = 1; off < 64; off <<= 1) {
      v0 += __shfl_xor(v0, off); v1 += __shfl_xor(v1, off);
      v2 += __shfl_xor(v2, off); v3 += __shfl_xor(v3, off);
      v4 += __shfl_xor(v4, off); v5 += __shfl_xor(v5, off);
      v6 += __shfl_xor(v6, off); v7 += __shfl_xor(v7, off);
    }
    if (t == 0) {
      SRT[0] = v0; SRT[1] = v1; SRT[2] = v2; SRT[3] = v3;
      SRT[4] = v4; SRT[5] = v5; SRT[6] = v6; SRT[7] = v7;
    }
  }
  __syncthreads();

  // ---- conv: each thread = 2 filters (n0,n0+1) x 4 tt ----
  int wv = t >> 6, j = t & 63;
  int fo_l = wv >> 1, n0 = (wv & 1) * 2;
  float acc0[4] = {0.f, 0.f, 0.f, 0.f}, acc1[4] = {0.f, 0.f, 0.f, 0.f};
#pragma unroll
  for (int lr8 = 0; lr8 < 8; ++lr8) {
    const float4* rb = xs4 + (fo_l * 8 + lr8) * 132;
    float4 X0 = rb[FL4(2 * j)];
    float4 X1 = rb[FL4(2 * j + 1)];
    float4 X2 = rb[FL4(2 * j + 2)];
    float4 X3 = rb[FL4(2 * j + 3)];
    float xq[16] = {X0.x, X0.y, X0.z, X0.w, X1.x, X1.y, X1.z, X1.w,
                    X2.x, X2.y, X2.z, X2.w, X3.x, X3.y, X3.z, X3.w};
    const float4* wb = (const float4*)&wsm[((fo_l * 8 + lr8) * 4 + n0) * 8];
    float4 Wa0 = wb[0], Wa1 = wb[1], Wb0 = wb[2], Wb1 = wb[3];
    float wA[7] = {Wa0.x, Wa0.y, Wa0.z, Wa0.w, Wa1.x, Wa1.y, Wa1.z};
    float wB[7] = {Wb0.x, Wb0.y, Wb0.z, Wb0.w, Wb1.x, Wb1.y, Wb1.z};
#pragma unroll
    for (int w = 0; w < 7; ++w) {
#pragma unroll
      for (int s = 0; s < 4; ++s) {
        float xv = xq[2 * s + w + 1];  // q = 2*tt + w + 1, tt = 4j+s
        acc0[s] += xv * wA[w];
        acc1[s] += xv * wB[w];
      }
    }
  }

  // ---- per-channel affine from SRT (wave-uniform -> scalar ops) ----
  int o0 = g * Nc + n0;
  float m0 = SRT[n0] * Minv, E0 = SRT[4 + n0] * Minv;
  float a0 = gamma[o0] * rsqrtf(E0 - m0 * m0 + EPSf);   // biased var
  float c0 = 56.0f * (beta[o0] - a0 * m0);              // 2*D*W = 56 pooled
  float m1 = SRT[n0 + 1] * Minv, E1 = SRT[4 + n0 + 1] * Minv;
  float a1 = gamma[o0 + 1] * rsqrtf(E1 - m1 * m1 + EPSf);
  float c1 = 56.0f * (beta[o0 + 1] - a1 * m1);

  int fo = fo2 * 2 + fo_l;
  float4 r0, r1;
  float u;
  u = a0 * acc0[0] + c0; r0.x = (u >= 0.f) ? u : LEAKYf * u;
  u = a0 * acc0[1] + c0; r0.y = (u >= 0.f) ? u : LEAKYf * u;
  u = a0 * acc0[2] + c0; r0.z = (u >= 0.f) ? u : LEAKYf * u;
  u = a0 * acc0[3] + c0; r0.w = (u >= 0.f) ? u : LEAKYf * u;
  u = a1 * acc1[0] + c1; r1.x = (u >= 0.f) ? u : LEAKYf * u;
  u = a1 * acc1[1] + c1; r1.y = (u >= 0.f) ? u : LEAKYf * u;
  u = a1 * acc1[2] + c1; r1.z = (u >= 0.f) ? u : LEAKYf * u;
  u = a1 * acc1[3] + c1; r1.w = (u >= 0.f) ? u : LEAKYf * u;
  *(float4*)(out + ((size_t)((b * Oc + o0) * FOc + fo)) * TTc + 4 * j) = r0;
  *(float4*)(out + ((size_t)((b * Oc + o0 + 1) * FOc + fo)) * TTc + 4 * j) = r1;
}

extern "C" void kernel_launch(void* const* d_in, const int* in_sizes, int n_in,
                              void* d_out, int out_size, void* d_ws, size_t ws_size,
                              hipStream_t stream) {
  (void)in_sizes; (void)n_in; (void)out_size; (void)ws_size;
  const float* x     = (const float*)d_in[0];
  const float* w     = (const float*)d_in[1];
  const float* gamma = (const float*)d_in[2];
  const float* beta  = (const float*)d_in[3];
  float* partials = (float*)d_ws;               // 1024*8 floats (32 KB)
  stats_k<<<dim3(Bc * Gc * 32), dim3(256), 0, stream>>>(x, w, partials);
  conv_k<<<dim3(Bc * Gc * 32), dim3(256), 0, stream>>>(x, w, partials, gamma,
                                                       beta, (float*)d_out);
}